// Round 2
// baseline (1217.337 us; speedup 1.0000x reference)
//
#include <hip/hip_runtime.h>

typedef _Float16 half8 __attribute__((ext_vector_type(8)));
typedef float floatx4 __attribute__((ext_vector_type(4)));

#define NSTEPS 512
#define IN_F   23
#define HSTRIDE 72   // LDS row stride in fp16 elements (64 + 8 pad), 144 B (16B-aligned)

__device__ __forceinline__ float fast_rcp(float x) { return __builtin_amdgcn_rcpf(x); }
__device__ __forceinline__ float fast_sigmoid(float x) { return fast_rcp(1.f + __expf(-x)); }
__device__ __forceinline__ float fast_tanh(float x) { return 2.f * fast_rcp(1.f + __expf(-2.f * x)) - 1.f; }

// 3-product split-precision accumulate: acc += (Ahi+Alo)*(Bhi+Blo), dropping lo*lo
#define MFMA3(acc, Ahi, Alo, Bhi, Blo)                                             \
    acc = __builtin_amdgcn_mfma_f32_16x16x32_f16((Ahi), (Bhi), (acc), 0, 0, 0);    \
    acc = __builtin_amdgcn_mfma_f32_16x16x32_f16((Ahi), (Blo), (acc), 0, 0, 0);    \
    acc = __builtin_amdgcn_mfma_f32_16x16x32_f16((Alo), (Bhi), (acc), 0, 0, 0);

__global__ __launch_bounds__(256, 1)
void lstm2_fused(const float* __restrict__ x,
                 const float* __restrict__ Wih0, const float* __restrict__ Whh0,
                 const float* __restrict__ bih0, const float* __restrict__ bhh0,
                 const float* __restrict__ Wih1, const float* __restrict__ Whh1,
                 const float* __restrict__ bih1, const float* __restrict__ bhh1,
                 const float* __restrict__ fcw, const float* __restrict__ fcb,
                 float* __restrict__ out)
{
    __shared__ _Float16 h0hi_lds[16 * HSTRIDE];
    __shared__ _Float16 h0lo_lds[16 * HSTRIDE];
    __shared__ _Float16 h1hi_lds[16 * HSTRIDE];
    __shared__ _Float16 h1lo_lds[16 * HSTRIDE];
    __shared__ float red[4][16];

    const int tid  = threadIdx.x;
    const int w    = tid >> 6;      // wave 0..3 -> hidden units [16w, 16w+16)
    const int lane = tid & 63;
    const int l15  = lane & 15;     // A row (batch tile row) / B col / C col (hidden)
    const int krow = lane >> 4;     // k-group 0..3
    const int b0   = blockIdx.x * 8;

    // ---- loop-invariant weight fragments, hi/lo split ----
    // B-operand layout: n = l15, k = krow*8 + j (any consistent bijection is fine
    // since A uses the same convention and sum over k is permutation-invariant).
    half8 wih0h[4],    wih0l[4];
    half8 whh0h[4][2], whh0l[4][2];
    half8 wih1h[4][2], wih1l[4][2];
    half8 whh1h[4][2], whh1l[4][2];
    float bias0[4], bias1[4];

    #pragma unroll
    for (int q = 0; q < 4; ++q) {
        const int g = q * 64 + w * 16 + l15;   // gate row (i,f,g,o blocks of 64)
        #pragma unroll
        for (int j = 0; j < 8; ++j) {
            const int k = krow * 8 + j;
            const float v = (k < IN_F) ? Wih0[g * IN_F + k] : 0.f;
            const _Float16 hi = (_Float16)v;
            wih0h[q][j] = hi;
            wih0l[q][j] = (_Float16)(v - (float)hi);
        }
        #pragma unroll
        for (int kk = 0; kk < 2; ++kk) {
            #pragma unroll
            for (int j = 0; j < 8; ++j) {
                const int k = kk * 32 + krow * 8 + j;
                float v;
                _Float16 hi;
                v = Whh0[g * 64 + k]; hi = (_Float16)v;
                whh0h[q][kk][j] = hi; whh0l[q][kk][j] = (_Float16)(v - (float)hi);
                v = Wih1[g * 64 + k]; hi = (_Float16)v;
                wih1h[q][kk][j] = hi; wih1l[q][kk][j] = (_Float16)(v - (float)hi);
                v = Whh1[g * 64 + k]; hi = (_Float16)v;
                whh1h[q][kk][j] = hi; whh1l[q][kk][j] = (_Float16)(v - (float)hi);
            }
        }
        bias0[q] = bih0[g] + bhh0[g];
        bias1[q] = bih1[g] + bhh1[g];
    }
    const float fcwv = fcw[w * 16 + l15];

    // ---- state ----
    floatx4 c0 = {0.f, 0.f, 0.f, 0.f};
    floatx4 c1 = {0.f, 0.f, 0.f, 0.f};
    half8 h0a0h, h0a1h, h0a0l, h0a1l;
    half8 h1a0h, h1a1h, h1a0l, h1a1l;
    #pragma unroll
    for (int j = 0; j < 8; ++j) {
        h0a0h[j] = (_Float16)0.f; h0a1h[j] = (_Float16)0.f;
        h0a0l[j] = (_Float16)0.f; h0a1l[j] = (_Float16)0.f;
        h1a0h[j] = (_Float16)0.f; h1a1h[j] = (_Float16)0.f;
        h1a0l[j] = (_Float16)0.f; h1a1l[j] = (_Float16)0.f;
    }

    // x A-fragment: row = l15 -> batch b0 + (l15 & 7) (rows 8..15 duplicate 0..7)
    const float* xrow = x + (size_t)(b0 + (l15 & 7)) * (NSTEPS * IN_F);
    float xf[8], xfn[8];
    #pragma unroll
    for (int j = 0; j < 8; ++j) {
        const int k = krow * 8 + j;
        xf[j] = (k < IN_F) ? xrow[k] : 0.f;   // t = 0
    }

    for (int t = 0; t < NSTEPS; ++t) {
        half8 xah, xal;
        #pragma unroll
        for (int j = 0; j < 8; ++j) {
            const _Float16 hi = (_Float16)xf[j];
            xah[j] = hi;
            xal[j] = (_Float16)(xf[j] - (float)hi);
        }

        // prefetch x for next step (hidden under this step's compute)
        {
            const int tn = (t + 1 < NSTEPS) ? (t + 1) : t;
            #pragma unroll
            for (int j = 0; j < 8; ++j) {
                const int k = krow * 8 + j;
                xfn[j] = (k < IN_F) ? xrow[tn * IN_F + k] : 0.f;
            }
        }

        // ---- layer 0 gates: x@Wih0^T + h0@Whh0^T + bias ----
        floatx4 acc[4];
        #pragma unroll
        for (int q = 0; q < 4; ++q) {
            floatx4 a = {bias0[q], bias0[q], bias0[q], bias0[q]};
            MFMA3(a, xah,   xal,   wih0h[q],    wih0l[q]);
            MFMA3(a, h0a0h, h0a0l, whh0h[q][0], whh0l[q][0]);
            MFMA3(a, h0a1h, h0a1l, whh0h[q][1], whh0l[q][1]);
            acc[q] = a;
        }

        float h0v[4];
        #pragma unroll
        for (int r = 0; r < 4; ++r) {
            const float iv = fast_sigmoid(acc[0][r]);
            const float fv = fast_sigmoid(acc[1][r]);
            const float gv = fast_tanh(acc[2][r]);
            const float ov = fast_sigmoid(acc[3][r]);
            const float cn = fv * c0[r] + iv * gv;
            c0[r] = cn;
            h0v[r] = ov * fast_tanh(cn);
        }
        #pragma unroll
        for (int r = 0; r < 4; ++r) {
            const int idx = (krow * 4 + r) * HSTRIDE + w * 16 + l15;
            const _Float16 hi = (_Float16)h0v[r];
            h0hi_lds[idx] = hi;
            h0lo_lds[idx] = (_Float16)(h0v[r] - (float)hi);
        }
        __syncthreads();
        // A-frags of new h0 (used now for layer1 input, and next step for layer0 recurrence)
        h0a0h = *(const half8*)&h0hi_lds[l15 * HSTRIDE + krow * 8];
        h0a1h = *(const half8*)&h0hi_lds[l15 * HSTRIDE + 32 + krow * 8];
        h0a0l = *(const half8*)&h0lo_lds[l15 * HSTRIDE + krow * 8];
        h0a1l = *(const half8*)&h0lo_lds[l15 * HSTRIDE + 32 + krow * 8];

        // ---- layer 1 gates ----
        #pragma unroll
        for (int q = 0; q < 4; ++q) {
            floatx4 a = {bias1[q], bias1[q], bias1[q], bias1[q]};
            MFMA3(a, h0a0h, h0a0l, wih1h[q][0], wih1l[q][0]);
            MFMA3(a, h0a1h, h0a1l, wih1h[q][1], wih1l[q][1]);
            MFMA3(a, h1a0h, h1a0l, whh1h[q][0], whh1l[q][0]);
            MFMA3(a, h1a1h, h1a1l, whh1h[q][1], whh1l[q][1]);
            acc[q] = a;
        }

        float h1v[4];
        #pragma unroll
        for (int r = 0; r < 4; ++r) {
            const float iv = fast_sigmoid(acc[0][r]);
            const float fv = fast_sigmoid(acc[1][r]);
            const float gv = fast_tanh(acc[2][r]);
            const float ov = fast_sigmoid(acc[3][r]);
            const float cn = fv * c1[r] + iv * gv;
            c1[r] = cn;
            h1v[r] = ov * fast_tanh(cn);
        }
        #pragma unroll
        for (int r = 0; r < 4; ++r) {
            const int idx = (krow * 4 + r) * HSTRIDE + w * 16 + l15;
            const _Float16 hi = (_Float16)h1v[r];
            h1hi_lds[idx] = hi;
            h1lo_lds[idx] = (_Float16)(h1v[r] - (float)hi);
        }
        __syncthreads();
        h1a0h = *(const half8*)&h1hi_lds[l15 * HSTRIDE + krow * 8];
        h1a1h = *(const half8*)&h1hi_lds[l15 * HSTRIDE + 32 + krow * 8];
        h1a0l = *(const half8*)&h1lo_lds[l15 * HSTRIDE + krow * 8];
        h1a1l = *(const half8*)&h1lo_lds[l15 * HSTRIDE + 32 + krow * 8];

        #pragma unroll
        for (int j = 0; j < 8; ++j) xf[j] = xfn[j];

        // ---- final step: FC on last h of layer 1 ----
        if (t == NSTEPS - 1) {
            float p[4];
            #pragma unroll
            for (int r = 0; r < 4; ++r) p[r] = h1v[r] * fcwv;
            #pragma unroll
            for (int off = 1; off < 16; off <<= 1) {
                #pragma unroll
                for (int r = 0; r < 4; ++r)
                    p[r] += __shfl_xor(p[r], off, 64);
            }
            if (l15 == 0) {
                #pragma unroll
                for (int r = 0; r < 4; ++r)
                    red[w][krow * 4 + r] = p[r];
            }
            __syncthreads();
            if (tid < 8) {
                float v = fcb[0];
                v += red[0][tid] + red[1][tid] + red[2][tid] + red[3][tid];
                out[b0 + tid] = v;
            }
        }
    }
}

extern "C" void kernel_launch(void* const* d_in, const int* in_sizes, int n_in,
                              void* d_out, int out_size, void* d_ws, size_t ws_size,
                              hipStream_t stream) {
    (void)n_in; (void)d_ws; (void)ws_size; (void)out_size;
    const float* xp    = (const float*)d_in[0];
    const float* Wih0  = (const float*)d_in[1];
    const float* Whh0  = (const float*)d_in[2];
    const float* bih0  = (const float*)d_in[3];
    const float* bhh0  = (const float*)d_in[4];
    const float* Wih1  = (const float*)d_in[5];
    const float* Whh1  = (const float*)d_in[6];
    const float* bih1  = (const float*)d_in[7];
    const float* bhh1  = (const float*)d_in[8];
    const float* fcw   = (const float*)d_in[9];
    const float* fcb   = (const float*)d_in[10];
    float* outp        = (float*)d_out;

    const int B = in_sizes[0] / (NSTEPS * IN_F);   // 2048
    const int nblocks = B / 8;                     // 256
    hipLaunchKernelGGL(lstm2_fused, dim3(nblocks), dim3(256), 0, stream,
                       xp, Wih0, Whh0, bih0, bhh0, Wih1, Whh1, bih1, bhh1,
                       fcw, fcb, outp);
}

// Round 3
// 846.601 us; speedup vs baseline: 1.4379x; 1.4379x over previous
//
#include <hip/hip_runtime.h>

typedef _Float16 half8 __attribute__((ext_vector_type(8)));
typedef float floatx4 __attribute__((ext_vector_type(4)));

#define NSTEPS 512
#define IN_F   23
#define HSTRIDE 72   // LDS row stride in fp16 elements (64 + 8 pad)

__device__ __forceinline__ float fast_rcp(float x) { return __builtin_amdgcn_rcpf(x); }
__device__ __forceinline__ float fast_sigmoid(float x) { return fast_rcp(1.f + __expf(-x)); }
__device__ __forceinline__ float fast_tanh(float x) { return 2.f * fast_rcp(1.f + __expf(-2.f * x)) - 1.f; }

// 3-product split-precision accumulate: acc += (Ahi+Alo)*(Bhi+Blo), dropping lo*lo
#define MFMA3(acc, Ahi, Alo, Bhi, Blo)                                             \
    acc = __builtin_amdgcn_mfma_f32_16x16x32_f16((Ahi), (Bhi), (acc), 0, 0, 0);    \
    acc = __builtin_amdgcn_mfma_f32_16x16x32_f16((Ahi), (Blo), (acc), 0, 0, 0);    \
    acc = __builtin_amdgcn_mfma_f32_16x16x32_f16((Alo), (Bhi), (acc), 0, 0, 0);

// 8 waves: waves 0-3 (grp=0) compute layer 0 at step i; waves 4-7 (grp=1)
// compute layer 1 at step i-1 (1-step skew pipeline). h0/h1 pass through
// double-buffered LDS; one barrier per iteration. Weight fragments are
// register-unified across groups so VGPR = max(group) not sum.
__global__ __launch_bounds__(512, 1)
void lstm2_fused(const float* __restrict__ x,
                 const float* __restrict__ Wih0, const float* __restrict__ Whh0,
                 const float* __restrict__ bih0, const float* __restrict__ bhh0,
                 const float* __restrict__ Wih1, const float* __restrict__ Whh1,
                 const float* __restrict__ bih1, const float* __restrict__ bhh1,
                 const float* __restrict__ fcw, const float* __restrict__ fcb,
                 float* __restrict__ out)
{
    __shared__ _Float16 hhi[2][2][16 * HSTRIDE];   // [layer][buf][...]
    __shared__ _Float16 hlo[2][2][16 * HSTRIDE];
    __shared__ float red[4][16];

    const int tid  = threadIdx.x;
    const int w8   = tid >> 6;        // 0..7
    const int grp  = w8 >> 2;         // 0: layer0 producer, 1: layer1 consumer
    const int wg   = w8 & 3;          // wave-in-group -> hidden units [16wg,16wg+16)
    const int lane = tid & 63;
    const int l15  = lane & 15;       // A row (batch) / B col / C col (hidden)
    const int krow = lane >> 4;       // k-group 0..3
    const int b0   = blockIdx.x * 8;

    // ---- weights (hi/lo split), register-unified across groups ----
    // grp0: wi[q][0] = Wih0 (k<32 covers IN=23), wi[q][1] = 0; wh = Whh0
    // grp1: wi = Wih1 (k=64, 2 frags);                         wh = Whh1
    half8 wi_h[4][2], wi_l[4][2], wh_h[4][2], wh_l[4][2];
    float bias[4];
    {
        const float* WI = grp ? Wih1 : Wih0;
        const float* WH = grp ? Whh1 : Whh0;
        const float* BI = grp ? bih1 : bih0;
        const float* BH = grp ? bhh1 : bhh0;
        #pragma unroll
        for (int q = 0; q < 4; ++q) {
            const int g = q * 64 + wg * 16 + l15;   // gate row
            if (!grp) {
                #pragma unroll
                for (int j = 0; j < 8; ++j) {
                    const int k = krow * 8 + j;
                    const float v = (k < IN_F) ? WI[g * IN_F + k] : 0.f;
                    const _Float16 hi = (_Float16)v;
                    wi_h[q][0][j] = hi;
                    wi_l[q][0][j] = (_Float16)(v - (float)hi);
                    wi_h[q][1][j] = (_Float16)0.f;
                    wi_l[q][1][j] = (_Float16)0.f;
                }
            } else {
                #pragma unroll
                for (int kk = 0; kk < 2; ++kk) {
                    #pragma unroll
                    for (int j = 0; j < 8; ++j) {
                        const int k = kk * 32 + krow * 8 + j;
                        const float v = WI[g * 64 + k];
                        const _Float16 hi = (_Float16)v;
                        wi_h[q][kk][j] = hi;
                        wi_l[q][kk][j] = (_Float16)(v - (float)hi);
                    }
                }
            }
            #pragma unroll
            for (int kk = 0; kk < 2; ++kk) {
                #pragma unroll
                for (int j = 0; j < 8; ++j) {
                    const int k = kk * 32 + krow * 8 + j;
                    const float v = WH[g * 64 + k];
                    const _Float16 hi = (_Float16)v;
                    wh_h[q][kk][j] = hi;
                    wh_l[q][kk][j] = (_Float16)(v - (float)hi);
                }
            }
            bias[q] = BI[g] + BH[g];
        }
    }
    const float fcwv = fcw[wg * 16 + l15];

    // ---- state ----
    floatx4 c = {0.f, 0.f, 0.f, 0.f};
    half8 in0h, in0l, in1h, in1l;     // input operand (grp0: x; grp1: h0)
    half8 hr0h, hr0l, hr1h, hr1l;     // recurrent operand (grp0: h0; grp1: h1)
    #pragma unroll
    for (int j = 0; j < 8; ++j) {
        in0h[j] = (_Float16)0.f; in0l[j] = (_Float16)0.f;
        in1h[j] = (_Float16)0.f; in1l[j] = (_Float16)0.f;
        hr0h[j] = (_Float16)0.f; hr0l[j] = (_Float16)0.f;
        hr1h[j] = (_Float16)0.f; hr1l[j] = (_Float16)0.f;
    }

    // x stream (grp0 only): A row l15 -> batch b0 + (l15 & 7)
    const float* xrow = x + (size_t)(b0 + (l15 & 7)) * (NSTEPS * IN_F);
    float xf[8], xfn[8];
    if (!grp) {
        #pragma unroll
        for (int j = 0; j < 8; ++j) {
            const int k = krow * 8 + j;
            xf[j] = (k < IN_F) ? xrow[k] : 0.f;   // t = 0
        }
    }

    float hv[4] = {0.f, 0.f, 0.f, 0.f};

    for (int i = 0; i <= NSTEPS; ++i) {
        const bool act = grp ? (i >= 1) : (i < NSTEPS);
        if (act) {
            if (!grp) {
                // split x(i) into hi/lo fragments; prefetch x(i+1)
                #pragma unroll
                for (int j = 0; j < 8; ++j) {
                    const _Float16 hi = (_Float16)xf[j];
                    in0h[j] = hi;
                    in0l[j] = (_Float16)(xf[j] - (float)hi);
                }
                const int tn = (i + 1 < NSTEPS) ? (i + 1) : i;
                #pragma unroll
                for (int j = 0; j < 8; ++j) {
                    const int k = krow * 8 + j;
                    xfn[j] = (k < IN_F) ? xrow[(size_t)tn * IN_F + k] : 0.f;
                }
            }

            floatx4 acc[4];
            #pragma unroll
            for (int q = 0; q < 4; ++q) {
                floatx4 a = {bias[q], bias[q], bias[q], bias[q]};
                MFMA3(a, in0h, in0l, wi_h[q][0], wi_l[q][0]);
                if (grp) { MFMA3(a, in1h, in1l, wi_h[q][1], wi_l[q][1]); }
                MFMA3(a, hr0h, hr0l, wh_h[q][0], wh_l[q][0]);
                MFMA3(a, hr1h, hr1l, wh_h[q][1], wh_l[q][1]);
                acc[q] = a;
            }

            #pragma unroll
            for (int r = 0; r < 4; ++r) {
                const float iv = fast_sigmoid(acc[0][r]);
                const float fv = fast_sigmoid(acc[1][r]);
                const float gv = fast_tanh(acc[2][r]);
                const float ov = fast_sigmoid(acc[3][r]);
                const float cn = fv * c[r] + iv * gv;
                c[r] = cn;
                hv[r] = ov * fast_tanh(cn);
            }

            // write h(step) to this layer's buffer: grp0 step i -> buf[i&1];
            // grp1 step i-1 -> buf[(i-1)&1]
            const int wb = grp ? ((i - 1) & 1) : (i & 1);
            _Float16* dsthi = &hhi[grp][wb][0];
            _Float16* dstlo = &hlo[grp][wb][0];
            #pragma unroll
            for (int r = 0; r < 4; ++r) {
                const int idx = (krow * 4 + r) * HSTRIDE + wg * 16 + l15;
                const _Float16 hi = (_Float16)hv[r];
                dsthi[idx] = hi;
                dstlo[idx] = (_Float16)(hv[r] - (float)hi);
            }
        }

        __syncthreads();

        // post-barrier fragment reads (A-operand layout: row=l15, k=krow*8+j)
        if (!grp) {
            if (i < NSTEPS) {   // h0(i) for step i+1 recurrence
                const _Float16* sh = &hhi[0][i & 1][0];
                const _Float16* sl = &hlo[0][i & 1][0];
                hr0h = *(const half8*)&sh[l15 * HSTRIDE + krow * 8];
                hr1h = *(const half8*)&sh[l15 * HSTRIDE + 32 + krow * 8];
                hr0l = *(const half8*)&sl[l15 * HSTRIDE + krow * 8];
                hr1l = *(const half8*)&sl[l15 * HSTRIDE + 32 + krow * 8];
                #pragma unroll
                for (int j = 0; j < 8; ++j) xf[j] = xfn[j];
            }
        } else {
            if (i < NSTEPS) {   // h0(i) as layer-1 input for step i (next iter)
                const _Float16* sh = &hhi[0][i & 1][0];
                const _Float16* sl = &hlo[0][i & 1][0];
                in0h = *(const half8*)&sh[l15 * HSTRIDE + krow * 8];
                in1h = *(const half8*)&sh[l15 * HSTRIDE + 32 + krow * 8];
                in0l = *(const half8*)&sl[l15 * HSTRIDE + krow * 8];
                in1l = *(const half8*)&sl[l15 * HSTRIDE + 32 + krow * 8];
            }
            if (i >= 1) {       // h1(i-1) for step i recurrence (next iter)
                const _Float16* sh = &hhi[1][(i - 1) & 1][0];
                const _Float16* sl = &hlo[1][(i - 1) & 1][0];
                hr0h = *(const half8*)&sh[l15 * HSTRIDE + krow * 8];
                hr1h = *(const half8*)&sh[l15 * HSTRIDE + 32 + krow * 8];
                hr0l = *(const half8*)&sl[l15 * HSTRIDE + krow * 8];
                hr1l = *(const half8*)&sl[l15 * HSTRIDE + 32 + krow * 8];
            }
        }
    }

    // ---- FC on last h1 (held by grp1 from its final iteration) ----
    if (grp) {
        float p[4];
        #pragma unroll
        for (int r = 0; r < 4; ++r) p[r] = hv[r] * fcwv;
        #pragma unroll
        for (int off = 1; off < 16; off <<= 1) {
            #pragma unroll
            for (int r = 0; r < 4; ++r)
                p[r] += __shfl_xor(p[r], off, 64);
        }
        if (l15 == 0) {
            #pragma unroll
            for (int r = 0; r < 4; ++r)
                red[wg][krow * 4 + r] = p[r];
        }
    }
    __syncthreads();
    if (tid < 8) {
        float v = fcb[0];
        v += red[0][tid] + red[1][tid] + red[2][tid] + red[3][tid];
        out[b0 + tid] = v;
    }
}

extern "C" void kernel_launch(void* const* d_in, const int* in_sizes, int n_in,
                              void* d_out, int out_size, void* d_ws, size_t ws_size,
                              hipStream_t stream) {
    (void)n_in; (void)d_ws; (void)ws_size; (void)out_size;
    const float* xp    = (const float*)d_in[0];
    const float* Wih0  = (const float*)d_in[1];
    const float* Whh0  = (const float*)d_in[2];
    const float* bih0  = (const float*)d_in[3];
    const float* bhh0  = (const float*)d_in[4];
    const float* Wih1  = (const float*)d_in[5];
    const float* Whh1  = (const float*)d_in[6];
    const float* bih1  = (const float*)d_in[7];
    const float* bhh1  = (const float*)d_in[8];
    const float* fcw   = (const float*)d_in[9];
    const float* fcb   = (const float*)d_in[10];
    float* outp        = (float*)d_out;

    const int B = in_sizes[0] / (NSTEPS * IN_F);   // 2048
    const int nblocks = B / 8;                     // 256
    hipLaunchKernelGGL(lstm2_fused, dim3(nblocks), dim3(512), 0, stream,
                       xp, Wih0, Whh0, bih0, bhh0, Wih1, Whh1, bih1, bhh1,
                       fcw, fcb, outp);
}

// Round 6
// 678.908 us; speedup vs baseline: 1.7931x; 1.2470x over previous
//
#include <hip/hip_runtime.h>

typedef _Float16 half8 __attribute__((ext_vector_type(8)));
typedef float floatx4 __attribute__((ext_vector_type(4)));

#define NSTEPS 512
#define IN_F   23
#define HSTRIDE 72   // LDS row stride in fp16 elements (64 + 8 pad), 16B-aligned rows

#define LOG2E      1.4426950408889634f
#define NEG2LOG2E -2.8853900817779268f

#if __has_builtin(__builtin_amdgcn_exp2f)
#define EXP2(x) __builtin_amdgcn_exp2f(x)
#else
#define EXP2(x) exp2f(x)
#endif

__device__ __forceinline__ float fast_rcp(float x) { return __builtin_amdgcn_rcpf(x); }

// split-precision accumulate with exact weights, f16-hi activations:
// acc += Ah * (Bhi + Blo)
#define MFMA2(acc, Ah, Bhi, Blo)                                                   \
    acc = __builtin_amdgcn_mfma_f32_16x16x32_f16((Ah), (Bhi), (acc), 0, 0, 0);     \
    acc = __builtin_amdgcn_mfma_f32_16x16x32_f16((Ah), (Blo), (acc), 0, 0, 0);

// 8 waves: waves 0-3 (grp=0) compute layer 0 at step i; waves 4-7 (grp=1)
// compute layer 1 at step i-1 (1-step skew pipeline). h passes through
// double-buffered LDS (f16 hi only); one barrier per iteration. Weight
// fragments are register-unified across groups so VGPR = max(group), not sum.
// Gate scales (log2e / 2log2e) are folded into weights+biases so activations
// use raw exp2: sigmoid = rcp(1+exp2(-z)), tanh = 2*rcp(1+exp2(-z)) - 1.
__global__ __launch_bounds__(512, 1)
void lstm2_fused(const float* __restrict__ x,
                 const float* __restrict__ Wih0, const float* __restrict__ Whh0,
                 const float* __restrict__ bih0, const float* __restrict__ bhh0,
                 const float* __restrict__ Wih1, const float* __restrict__ Whh1,
                 const float* __restrict__ bih1, const float* __restrict__ bhh1,
                 const float* __restrict__ fcw, const float* __restrict__ fcb,
                 float* __restrict__ out)
{
    __shared__ _Float16 hbuf[2][2][16 * HSTRIDE];   // [layer][buf][...]
    __shared__ float red[4][16];

    const int tid  = threadIdx.x;
    const int w8   = tid >> 6;        // 0..7
    const int grp  = w8 >> 2;         // 0: layer0 producer, 1: layer1 consumer
    const int wg   = w8 & 3;          // wave-in-group -> hidden units [16wg,16wg+16)
    const int lane = tid & 63;
    const int l15  = lane & 15;       // A row (batch) / B col / C col (hidden)
    const int krow = lane >> 4;       // k-group 0..3
    const int b0   = blockIdx.x * 8;

    // ---- weights (hi/lo split, gate-scaled), register-unified across groups ----
    // grp0: wi[q][0] = Wih0 (k<32 covers IN=23), wi[q][1] unused; wh = Whh0
    // grp1: wi = Wih1 (k=64, 2 frags);                            wh = Whh1
    half8 wi_h[4][2], wi_l[4][2], wh_h[4][2], wh_l[4][2];
    float bias[4];
    {
        const float* WI = grp ? Wih1 : Wih0;
        const float* WH = grp ? Whh1 : Whh0;
        const float* BI = grp ? bih1 : bih0;
        const float* BH = grp ? bhh1 : bhh0;
        const float gs[4] = {LOG2E, LOG2E, 2.f * LOG2E, LOG2E};
        #pragma unroll
        for (int q = 0; q < 4; ++q) {
            const int g = q * 64 + wg * 16 + l15;   // gate row
            if (!grp) {
                #pragma unroll
                for (int j = 0; j < 8; ++j) {
                    const int k = krow * 8 + j;
                    const float v = ((k < IN_F) ? WI[g * IN_F + k] : 0.f) * gs[q];
                    const _Float16 hi = (_Float16)v;
                    wi_h[q][0][j] = hi;
                    wi_l[q][0][j] = (_Float16)(v - (float)hi);
                    wi_h[q][1][j] = (_Float16)0.f;
                    wi_l[q][1][j] = (_Float16)0.f;
                }
            } else {
                #pragma unroll
                for (int kk = 0; kk < 2; ++kk) {
                    #pragma unroll
                    for (int j = 0; j < 8; ++j) {
                        const int k = kk * 32 + krow * 8 + j;
                        const float v = WI[g * 64 + k] * gs[q];
                        const _Float16 hi = (_Float16)v;
                        wi_h[q][kk][j] = hi;
                        wi_l[q][kk][j] = (_Float16)(v - (float)hi);
                    }
                }
            }
            #pragma unroll
            for (int kk = 0; kk < 2; ++kk) {
                #pragma unroll
                for (int j = 0; j < 8; ++j) {
                    const int k = kk * 32 + krow * 8 + j;
                    const float v = WH[g * 64 + k] * gs[q];
                    const _Float16 hi = (_Float16)v;
                    wh_h[q][kk][j] = hi;
                    wh_l[q][kk][j] = (_Float16)(v - (float)hi);
                }
            }
            bias[q] = (BI[g] + BH[g]) * gs[q];
        }
    }
    const float fcwv = fcw[wg * 16 + l15];

    // ---- state ----
    floatx4 c = {0.f, 0.f, 0.f, 0.f};
    half8 in0h, in1h;                 // input operand (grp0: x; grp1: h0)
    half8 hr0h, hr1h;                 // recurrent operand (grp0: h0; grp1: h1)
    #pragma unroll
    for (int j = 0; j < 8; ++j) {
        in0h[j] = (_Float16)0.f; in1h[j] = (_Float16)0.f;
        hr0h[j] = (_Float16)0.f; hr1h[j] = (_Float16)0.f;
    }

    // x stream (grp0 only): A row l15 -> batch b0 + (l15 & 7)
    const float* xrow = x + (size_t)(b0 + (l15 & 7)) * (NSTEPS * IN_F);
    float xf[8], xfn[8];
    if (!grp) {
        #pragma unroll
        for (int j = 0; j < 8; ++j) {
            const int k = krow * 8 + j;
            xf[j] = (k < IN_F) ? xrow[k] : 0.f;   // t = 0
        }
    }

    float hv[4] = {0.f, 0.f, 0.f, 0.f};

    for (int i = 0; i <= NSTEPS; ++i) {
        const bool act = grp ? (i >= 1) : (i < NSTEPS);
        if (act) {
            if (!grp) {
                // cast x(i) to f16-hi fragment; prefetch x(i+1)
                #pragma unroll
                for (int j = 0; j < 8; ++j) in0h[j] = (_Float16)xf[j];
                const int tn = (i + 1 < NSTEPS) ? (i + 1) : i;
                #pragma unroll
                for (int j = 0; j < 8; ++j) {
                    const int k = krow * 8 + j;
                    xfn[j] = (k < IN_F) ? xrow[(size_t)tn * IN_F + k] : 0.f;
                }
            }

            floatx4 acc[4];
            #pragma unroll
            for (int q = 0; q < 4; ++q) {
                floatx4 a = {bias[q], bias[q], bias[q], bias[q]};
                MFMA2(a, in0h, wi_h[q][0], wi_l[q][0]);
                if (grp) { MFMA2(a, in1h, wi_h[q][1], wi_l[q][1]); }
                MFMA2(a, hr0h, wh_h[q][0], wh_l[q][0]);
                MFMA2(a, hr1h, wh_h[q][1], wh_l[q][1]);
                acc[q] = a;
            }

            #pragma unroll
            for (int r = 0; r < 4; ++r) {
                const float iv = fast_rcp(1.f + EXP2(-acc[0][r]));
                const float fv = fast_rcp(1.f + EXP2(-acc[1][r]));
                const float gv = 2.f * fast_rcp(1.f + EXP2(-acc[2][r])) - 1.f;
                const float ov = fast_rcp(1.f + EXP2(-acc[3][r]));
                const float cn = fv * c[r] + iv * gv;
                c[r] = cn;
                hv[r] = ov * (2.f * fast_rcp(1.f + EXP2(NEG2LOG2E * cn)) - 1.f);
            }

            // write h(step) to this layer's buffer: grp0 step i -> buf[i&1];
            // grp1 step i-1 -> buf[(i-1)&1]
            const int wb = grp ? ((i - 1) & 1) : (i & 1);
            _Float16* dst = &hbuf[grp][wb][0];
            #pragma unroll
            for (int r = 0; r < 4; ++r) {
                const int idx = (krow * 4 + r) * HSTRIDE + wg * 16 + l15;
                dst[idx] = (_Float16)hv[r];
            }
        }

        __syncthreads();

        // post-barrier fragment reads (A-operand layout: row=l15, k=krow*8+j)
        if (!grp) {
            if (i < NSTEPS) {   // h0(i) for step i+1 recurrence
                const _Float16* sh = &hbuf[0][i & 1][0];
                hr0h = *(const half8*)&sh[l15 * HSTRIDE + krow * 8];
                hr1h = *(const half8*)&sh[l15 * HSTRIDE + 32 + krow * 8];
                #pragma unroll
                for (int j = 0; j < 8; ++j) xf[j] = xfn[j];
            }
        } else {
            if (i < NSTEPS) {   // h0(i) as layer-1 input for step i (next iter)
                const _Float16* sh = &hbuf[0][i & 1][0];
                in0h = *(const half8*)&sh[l15 * HSTRIDE + krow * 8];
                in1h = *(const half8*)&sh[l15 * HSTRIDE + 32 + krow * 8];
            }
            if (i >= 1) {       // h1(i-1) for step i recurrence (next iter)
                const _Float16* sh = &hbuf[1][(i - 1) & 1][0];
                hr0h = *(const half8*)&sh[l15 * HSTRIDE + krow * 8];
                hr1h = *(const half8*)&sh[l15 * HSTRIDE + 32 + krow * 8];
            }
        }
    }

    // ---- FC on last h1 (held by grp1 from its final iteration) ----
    if (grp) {
        float p[4];
        #pragma unroll
        for (int r = 0; r < 4; ++r) p[r] = hv[r] * fcwv;
        #pragma unroll
        for (int off = 1; off < 16; off <<= 1) {
            #pragma unroll
            for (int r = 0; r < 4; ++r)
                p[r] += __shfl_xor(p[r], off, 64);
        }
        if (l15 == 0) {
            #pragma unroll
            for (int r = 0; r < 4; ++r)
                red[wg][krow * 4 + r] = p[r];
        }
    }
    __syncthreads();
    if (tid < 8) {
        float v = fcb[0];
        v += red[0][tid] + red[1][tid] + red[2][tid] + red[3][tid];
        out[b0 + tid] = v;
    }
}

extern "C" void kernel_launch(void* const* d_in, const int* in_sizes, int n_in,
                              void* d_out, int out_size, void* d_ws, size_t ws_size,
                              hipStream_t stream) {
    (void)n_in; (void)d_ws; (void)ws_size; (void)out_size;
    const float* xp    = (const float*)d_in[0];
    const float* Wih0  = (const float*)d_in[1];
    const float* Whh0  = (const float*)d_in[2];
    const float* bih0  = (const float*)d_in[3];
    const float* bhh0  = (const float*)d_in[4];
    const float* Wih1  = (const float*)d_in[5];
    const float* Whh1  = (const float*)d_in[6];
    const float* bih1  = (const float*)d_in[7];
    const float* bhh1  = (const float*)d_in[8];
    const float* fcw   = (const float*)d_in[9];
    const float* fcb   = (const float*)d_in[10];
    float* outp        = (float*)d_out;

    const int B = in_sizes[0] / (NSTEPS * IN_F);   // 2048
    const int nblocks = B / 8;                     // 256
    hipLaunchKernelGGL(lstm2_fused, dim3(nblocks), dim3(512), 0, stream,
                       xp, Wih0, Whh0, bih0, bhh0, Wih1, Whh1, bih1, bhh1,
                       fcw, fcb, outp);
}